// Round 12
// baseline (359.819 us; speedup 1.0000x reference)
//
#include <hip/hip_runtime.h>
#include <hip/hip_bf16.h>

#define INDIM 128
#define HID 32
#define HID2 16                // channel pairs (bf16x2 per u32)
#define BN_EPS 1e-5f
#define BSH 8                  // 256 nodes per bucket
#define MAXB 512               // max buckets (n <= 131072)
#define PCHUNK 2048            // edges per partition block (20KB LDS -> 8 blocks/CU)
#define BNP 64                 // BN partial spread

// ---- bf16 pack/unpack (RNE pack; exact unpack) ----
static __device__ __forceinline__ unsigned pk2bf(float lo, float hi) {
    unsigned a = __float_as_uint(lo);
    unsigned b = __float_as_uint(hi);
    a = (a + 0x7fffu + ((a >> 16) & 1u)) >> 16;
    b = (b + 0x7fffu + ((b >> 16) & 1u)) & 0xffff0000u;
    return a | b;
}
static __device__ __forceinline__ float bflo(unsigned u) { return __uint_as_float(u << 16); }
static __device__ __forceinline__ float bfhi(unsigned u) { return __uint_as_float(u & 0xffff0000u); }

// ---- per-block int64 layout detection (is64 iff ALL 64 odd words zero) ----
static __device__ __forceinline__ int detect_is64(const int* __restrict__ ei, int t) {
    __shared__ int sh;
    if (t == 0) sh = 1;
    __syncthreads();
    if (t < 64 && ei[2 * t + 1] != 0) sh = 0;   // benign race, same value
    __syncthreads();
    return sh;
}

// ---------------------------------------------------------------- degree histogram (global atomics, E-parallel)
__global__ __launch_bounds__(256) void ge_deg(const int* __restrict__ ei,
                                              unsigned* __restrict__ deg, int E) {
    int t = threadIdx.x;
    int is64 = detect_is64(ei, t);
    int stride = gridDim.x * 256;
    if (is64) {
        const unsigned long long* p = (const unsigned long long*)ei;
        for (int e = blockIdx.x * 256 + t; e < E; e += stride)
            atomicAdd(&deg[(unsigned)p[E + e]], 1u);
    } else {
        for (int e = blockIdx.x * 256 + t; e < E; e += stride)
            atomicAdd(&deg[(unsigned)ei[E + e]], 1u);
    }
}

// ---------------------------------------------------------------- per-bucket local scan of deg
__global__ void ge_bkscan(const unsigned* __restrict__ deg, unsigned* __restrict__ rowst,
                          unsigned* __restrict__ bcnt, int n) {
    __shared__ unsigned s[256];
    int b = blockIdx.x, t = threadIdx.x;
    int node = (b << 8) + t;
    unsigned v = (node < n) ? deg[node] : 0u;
    s[t] = v;
    __syncthreads();
    for (int off = 1; off < 256; off <<= 1) {
        unsigned u = (t >= off) ? s[t - off] : 0u;
        __syncthreads();
        s[t] += u;
        __syncthreads();
    }
    if (node < n) rowst[node] = s[t] - v;      // bucket-local exclusive
    if (t == 255) bcnt[b] = s[255];            // bucket total
}

// ---------------------------------------------------------------- bucket scan (1 block)
__global__ void ge_bscan(const unsigned* __restrict__ bcnt, unsigned* __restrict__ bstart,
                         unsigned* __restrict__ bwptr, int nb, int E) {
    __shared__ unsigned s[MAXB];
    int t = threadIdx.x;                       // 512 threads
    unsigned v = (t < nb) ? bcnt[t] : 0u;
    s[t] = v;
    __syncthreads();
    for (int off = 1; off < MAXB; off <<= 1) {
        unsigned u = (t >= off) ? s[t - off] : 0u;
        __syncthreads();
        s[t] += u;
        __syncthreads();
    }
    if (t < nb) { unsigned ex = s[t] - v; bstart[t] = ex; bwptr[t] = ex; }
    if (t == 0) bstart[nb] = (unsigned)E;
}

// ---------------------------------------------------------------- finalize rowst/wptr/dinv (n-parallel)
__global__ __launch_bounds__(256) void ge_scan3(unsigned* __restrict__ rowst,
                                                const unsigned* __restrict__ bstart,
                                                unsigned* __restrict__ wptr,
                                                const unsigned* __restrict__ deg,
                                                float* __restrict__ dinv, int n) {
    int i = blockIdx.x * 256 + threadIdx.x;
    if (i >= n) return;
    unsigned r = rowst[i] + bstart[i >> BSH];
    rowst[i] = r;
    wptr[i] = r;
    dinv[i] = rsqrtf((float)(deg[i] + 1u));    // +1 self loop
}

// ---------------------------------------------------------------- partition edges into buckets
__global__ __launch_bounds__(256) void ge_bpart(const int* __restrict__ ei,
                                                unsigned* __restrict__ bwptr,
                                                uint2* __restrict__ ebuf, int E, int nb) {
    int t = threadIdx.x;
    int is64 = detect_is64(ei, t);
    __shared__ uint2 es[PCHUNK];
    __shared__ unsigned cnt[MAXB];
    __shared__ unsigned base[MAXB];
    int start = blockIdx.x * PCHUNK;
    int len = min(PCHUNK, E - start);
    cnt[t] = 0; cnt[t + 256] = 0;
    __syncthreads();
    if (is64) {
        const unsigned long long* p = (const unsigned long long*)ei;
        for (int i = t; i < len; i += 256) {
            unsigned s = (unsigned)p[start + i];
            unsigned d = (unsigned)p[E + start + i];
            es[i] = make_uint2(s, d);
            atomicAdd(&cnt[d >> BSH], 1u);
        }
    } else {
        for (int i = t; i < len; i += 256) {
            unsigned s = (unsigned)ei[start + i];
            unsigned d = (unsigned)ei[E + start + i];
            es[i] = make_uint2(s, d);
            atomicAdd(&cnt[d >> BSH], 1u);
        }
    }
    __syncthreads();
    for (int b = t; b < nb; b += 256) {
        unsigned c = cnt[b];
        base[b] = c ? atomicAdd(&bwptr[b], c) : 0u;
        cnt[b] = 0;                            // becomes cursor
    }
    __syncthreads();
    for (int i = t; i < len; i += 256) {
        uint2 e = es[i];
        unsigned b = e.y >> BSH;
        unsigned pos = base[b] + atomicAdd(&cnt[b], 1u);
        ebuf[pos] = e;
    }
}

// ---------------------------------------------------------------- CSR col fill from bucket-ordered ebuf
// ebuf is bucket-ordered: a block's edges target ~256 distinct dst whose col
// ranges are contiguous (~16KB window) -> write lines fill before eviction.
__global__ __launch_bounds__(256) void ge_fill2(const uint2* __restrict__ ebuf,
                                                unsigned* __restrict__ wptr,
                                                unsigned* __restrict__ col, int E) {
    int i = blockIdx.x * 256 + threadIdx.x;
    int stride = gridDim.x * 256;
    for (; i < E; i += stride) {
        uint2 e = ebuf[i];
        unsigned slot = atomicAdd(&wptr[e.y], 1u);
        col[slot] = e.x;
    }
}

// ---------------------------------------------------------------- g1 = bf16((x @ W1) * dinv)
// R5-measured form (45us): 1 thread/node, unroll-4, uniform W1 -> s_load.
__global__ __launch_bounds__(256) void ge_gemm1(const float* __restrict__ x,
                                                const float* __restrict__ W1,
                                                const float* __restrict__ dinv,
                                                unsigned* __restrict__ g1, int n) {
    int node = blockIdx.x * blockDim.x + threadIdx.x;
    if (node >= n) return;
    float acc[HID];
#pragma unroll
    for (int c = 0; c < HID; c++) acc[c] = 0.f;
    const float4* xr = (const float4*)(x + (size_t)node * INDIM);
#pragma unroll 4
    for (int k4 = 0; k4 < INDIM / 4; k4++) {
        float4 xv = xr[k4];
        const float* w = W1 + (size_t)k4 * 4 * HID;
#pragma unroll
        for (int kk = 0; kk < 4; kk++) {
            float xk = (&xv.x)[kk];
#pragma unroll
            for (int c = 0; c < HID; c++) acc[c] = fmaf(xk, w[kk * HID + c], acc[c]);
        }
    }
    float dv = dinv[node];
    unsigned og[HID2];
#pragma unroll
    for (int i = 0; i < HID2; i++) og[i] = pk2bf(acc[2 * i] * dv, acc[2 * i + 1] * dv);
    uint4* o4 = (uint4*)(g1 + (size_t)node * HID2);
#pragma unroll
    for (int i = 0; i < 4; i++)
        o4[i] = make_uint4(og[4 * i], og[4 * i + 1], og[4 * i + 2], og[4 * i + 3]);
}

// ---------------------------------------------------------------- gather (bf16 rows), optional BN-fuse
template<bool OUT_BF16, bool FUSE_BN>
__global__ __launch_bounds__(256) void ge_gather(const unsigned* __restrict__ g,
                                                 const unsigned* __restrict__ rowst,
                                                 const unsigned* __restrict__ deg,
                                                 const unsigned* __restrict__ col,
                                                 const float* __restrict__ dinv,
                                                 const float* __restrict__ bias,
                                                 unsigned* __restrict__ outb,
                                                 float* __restrict__ outf,
                                                 float* __restrict__ bnsum,
                                                 float* __restrict__ bnsq, int n) {
    int t = threadIdx.x;
    int idx = blockIdx.x * 256 + t;
    int node = idx >> 4, cp = idx & 15;
    float h0 = 0.f, h1v = 0.f;
    if (node < n) {
        unsigned self = g[(size_t)node * HID2 + cp];
        float a0 = bflo(self), a1 = bfhi(self);
        unsigned st = rowst[node], len = deg[node];
        unsigned j = 0;
        for (; j + 4 <= len; j += 4) {
            unsigned c0 = col[st + j + 0];
            unsigned c1 = col[st + j + 1];
            unsigned c2 = col[st + j + 2];
            unsigned c3 = col[st + j + 3];
            unsigned u0 = g[(size_t)c0 * HID2 + cp];
            unsigned u1 = g[(size_t)c1 * HID2 + cp];
            unsigned u2 = g[(size_t)c2 * HID2 + cp];
            unsigned u3 = g[(size_t)c3 * HID2 + cp];
            a0 += (bflo(u0) + bflo(u1)) + (bflo(u2) + bflo(u3));
            a1 += (bfhi(u0) + bfhi(u1)) + (bfhi(u2) + bfhi(u3));
        }
        for (; j < len; j++) {
            unsigned u = g[(size_t)col[st + j] * HID2 + cp];
            a0 += bflo(u); a1 += bfhi(u);
        }
        float dv = dinv[node];
        float2 bb = ((const float2*)bias)[cp];
        h0 = fmaf(dv, a0, bb.x);
        h1v = fmaf(dv, a1, bb.y);
        if (OUT_BF16) {
            outb[(size_t)node * HID2 + cp] = pk2bf(h0, h1v);
        } else {
            float2 o; o.x = h0; o.y = h1v;
            ((float2*)outf)[(size_t)node * HID2 + cp] = o;
        }
    }
    if (FUSE_BN) {
        __shared__ float4 red[256];
        red[t] = make_float4(h0, h0 * h0, h1v, h1v * h1v);
        __syncthreads();
        for (int off = 128; off >= 16; off >>= 1) {
            if (t < off) {
                float4 a = red[t], b = red[t + off];
                red[t] = make_float4(a.x + b.x, a.y + b.y, a.z + b.z, a.w + b.w);
            }
            __syncthreads();
        }
        if (t < 16) {
            float4 v = red[t];
            int p = blockIdx.x & (BNP - 1);
            atomicAdd(&bnsum[p * HID + 2 * t + 0], v.x);
            atomicAdd(&bnsq [p * HID + 2 * t + 0], v.y);
            atomicAdd(&bnsum[p * HID + 2 * t + 1], v.z);
            atomicAdd(&bnsq [p * HID + 2 * t + 1], v.w);
        }
    }
}

// ---------------------------------------------------------------- BN finalize -> affine a,b
__global__ void ge_bnfinal(const float* __restrict__ bnsum, const float* __restrict__ bnsq,
                           const float* __restrict__ gamma, const float* __restrict__ beta,
                           float* __restrict__ ab, int n) {
    int c = threadIdx.x;
    if (c >= HID) return;
    float s = 0.f, q = 0.f;
    for (int p = 0; p < BNP; p++) { s += bnsum[p * HID + c]; q += bnsq[p * HID + c]; }
    float inv_n = 1.f / (float)n;
    float mean = s * inv_n;
    float var = fmaxf(q * inv_n - mean * mean, 0.f);
    float iv = rsqrtf(var + BN_EPS);
    float a = gamma[c] * iv;
    ab[c] = a;
    ab[HID + c] = beta[c] - mean * a;
}

// ---------------------------------------------------------------- g2 = bf16((relu(a*h1+b) @ W2) * dinv)
__global__ __launch_bounds__(256) void ge_gemm2(const unsigned* __restrict__ h1,
                                                const float* __restrict__ W2,
                                                const float* __restrict__ ab,
                                                const float* __restrict__ dinv,
                                                unsigned* __restrict__ g2, int n) {
    int node = blockIdx.x * blockDim.x + threadIdx.x;
    if (node >= n) return;
    float p[HID];
    const uint4* hr = (const uint4*)(h1 + (size_t)node * HID2);
#pragma unroll
    for (int i4 = 0; i4 < 4; i4++) {
        uint4 u4 = hr[i4];
        const unsigned* u = &u4.x;
#pragma unroll
        for (int j = 0; j < 4; j++) {
            int k0 = (i4 * 4 + j) * 2, k1 = k0 + 1;
            p[k0] = fmaxf(fmaf(ab[k0], bflo(u[j]), ab[HID + k0]), 0.f);
            p[k1] = fmaxf(fmaf(ab[k1], bfhi(u[j]), ab[HID + k1]), 0.f);
        }
    }
    float acc[HID];
#pragma unroll
    for (int c = 0; c < HID; c++) acc[c] = 0.f;
#pragma unroll
    for (int k = 0; k < HID; k++) {
        float pk = p[k];
        const float* w = W2 + (size_t)k * HID;
#pragma unroll
        for (int c = 0; c < HID; c++) acc[c] = fmaf(pk, w[c], acc[c]);
    }
    float dv = dinv[node];
    unsigned og[HID2];
#pragma unroll
    for (int i = 0; i < HID2; i++) og[i] = pk2bf(acc[2 * i] * dv, acc[2 * i + 1] * dv);
    uint4* o4 = (uint4*)(g2 + (size_t)node * HID2);
#pragma unroll
    for (int i = 0; i < 4; i++)
        o4[i] = make_uint4(og[4 * i], og[4 * i + 1], og[4 * i + 2], og[4 * i + 3]);
}

// ================================================================ launch
extern "C" void kernel_launch(void* const* d_in, const int* in_sizes, int n_in,
                              void* d_out, int out_size, void* d_ws, size_t ws_size,
                              hipStream_t stream) {
    const float* x     = (const float*)d_in[0];
    const int*   ei    = (const int*)d_in[1];
    const float* W1    = (const float*)d_in[2];
    const float* b1    = (const float*)d_in[3];
    const float* gamma = (const float*)d_in[4];
    const float* beta  = (const float*)d_in[5];
    const float* W2    = (const float*)d_in[6];
    const float* b2    = (const float*)d_in[7];
    float* outp = (float*)d_out;

    const int n = in_sizes[0] / INDIM;        // 100000
    const int E = in_sizes[1] / 2;            // 1600000
    const int nb = (n + 255) >> 8;            // 391 buckets

    // ---- workspace carve-up (256B aligned) ----
    char* w = (char*)d_ws;
    size_t off = 0;
    auto nxt = [&](size_t b) -> void* {
        void* p = w + off;
        off += (b + 255) & ~(size_t)255;
        return p;
    };
    float*    bnsum   = (float*)nxt(BNP * HID * 4);
    float*    bnsq    = (float*)nxt(BNP * HID * 4);
    unsigned* deg     = (unsigned*)nxt((size_t)n * 4);
    size_t zero_end = off;                    // everything above starts at 0
    unsigned* bcnt    = (unsigned*)nxt(MAXB * 4);
    unsigned* bstart  = (unsigned*)nxt((MAXB + 1) * 4);
    unsigned* bwptr   = (unsigned*)nxt(MAXB * 4);
    unsigned* rowst   = (unsigned*)nxt((size_t)n * 4);
    unsigned* wptr    = (unsigned*)nxt((size_t)n * 4);
    float*    dinv    = (float*)nxt((size_t)n * 4);
    float*    ab      = (float*)nxt(2 * HID * 4);
    unsigned* colx    = (unsigned*)nxt((size_t)E * 4);
    unsigned* g1      = (unsigned*)nxt((size_t)n * HID2 * 4);   // bf16x2 packed
    unsigned* h1      = (unsigned*)nxt((size_t)n * HID2 * 4);   // bf16x2 packed
    unsigned* g2      = g1;                   // g1 dead after first gather
    uint2*    ebuf    = (uint2*)d_out;        // E*8B == out bytes; dead before last gather

    hipMemsetAsync(d_ws, 0, zero_end, stream);

    ge_deg<<<2048, 256, 0, stream>>>(ei, deg, E);
    ge_bkscan<<<nb, 256, 0, stream>>>(deg, rowst, bcnt, n);
    ge_bscan<<<1, MAXB, 0, stream>>>(bcnt, bstart, bwptr, nb, E);
    ge_scan3<<<(n + 255) / 256, 256, 0, stream>>>(rowst, bstart, wptr, deg, dinv, n);

    ge_bpart<<<(E + PCHUNK - 1) / PCHUNK, 256, 0, stream>>>(ei, bwptr, ebuf, E, nb);
    ge_fill2<<<2048, 256, 0, stream>>>(ebuf, wptr, colx, E);

    ge_gemm1<<<(n + 255) / 256, 256, 0, stream>>>(x, W1, dinv, g1, n);

    int gbl = ((n * HID2) + 255) / 256;
    ge_gather<true, true><<<gbl, 256, 0, stream>>>(g1, rowst, deg, colx, dinv, b1,
                                                   h1, nullptr, bnsum, bnsq, n);
    ge_bnfinal<<<1, 64, 0, stream>>>(bnsum, bnsq, gamma, beta, ab, n);

    ge_gemm2<<<(n + 255) / 256, 256, 0, stream>>>(h1, W2, ab, dinv, g2, n);

    ge_gather<false, false><<<gbl, 256, 0, stream>>>(g2, rowst, deg, colx, dinv, b2,
                                                     nullptr, outp, nullptr, nullptr, n);
}